// Round 16
// baseline (101.101 us; speedup 1.0000x reference)
//
#include <hip/hip_runtime.h>
#include <hip/hip_bf16.h>
#include <math.h>

#define DIM 256
#define HDIM 32
#define NN 4096
#define NM (NN * DIM)
// (1/sqrt(256)) * log2(e) -- folded into WQ so scores are in exp2 domain
#define PREF 0.09016844005555896f
#define LEAKY 0.2f
#define BCAP 128   // edge-bucket capacity per dst (Poisson(32): P(deg>128) ~ 0)

typedef __attribute__((ext_vector_type(8))) short short8;
typedef __attribute__((ext_vector_type(16))) float f32x16;

#if __has_builtin(__builtin_amdgcn_exp2f)
#define EXP2(x) __builtin_amdgcn_exp2f(x)   // raw v_exp_f32: scores bounded, no fixups needed
#else
#define EXP2(x) exp2f(x)
#endif

static __device__ __forceinline__ unsigned bfbits(float x) {
  unsigned u = __float_as_uint(x);
  return (u + 0x7fffu + ((u >> 16) & 1u)) >> 16;   // RNE f32->bf16 bits
}
static __device__ __forceinline__ float bf2f(unsigned short b) {
  return __uint_as_float(((unsigned)b) << 16);
}
static __device__ __forceinline__ unsigned pk_bf16(float lo, float hi) {
  __hip_bfloat162 t = __float22bfloat162_rn(make_float2(lo, hi));  // v_cvt_pk_bf16_f32
  return *(unsigned*)&t;
}

// ---- convert: Wtb[w][n][k] = bf16(W_w[k][n]*scale); grid (16,4); y==0 blocks zero cnt
__global__ __launch_bounds__(256) void convert_w(
    const float* __restrict__ W0, const float* __restrict__ W1,
    const float* __restrict__ W2, const float* __restrict__ W3,
    unsigned short* __restrict__ Wtb, int* __restrict__ cnt) {
  const int tid = threadIdx.x;
  if (blockIdx.y == 0) cnt[blockIdx.x * 256 + tid] = 0;   // 16x256 = 4096 ints
  __shared__ float tile[64][68];
  const int wsel = blockIdx.y;
  const float* W = wsel == 0 ? W0 : (wsel == 1 ? W1 : (wsel == 2 ? W2 : W3));
  const float scale = wsel == 0 ? PREF : 1.f;
  const int kb = (blockIdx.x & 3) * 64, nb = (blockIdx.x >> 2) * 64;
#pragma unroll
  for (int i = 0; i < 4; ++i) {
    int idx = i * 256 + tid;
    int kr = idx >> 4, ns = idx & 15;
    float4 v = *(const float4*)&W[(kb + kr) * DIM + nb + ns * 4];
    tile[kr][ns * 4 + 0] = v.x; tile[kr][ns * 4 + 1] = v.y;
    tile[kr][ns * 4 + 2] = v.z; tile[kr][ns * 4 + 3] = v.w;
  }
  __syncthreads();
  unsigned short* o = Wtb + wsel * 65536;
#pragma unroll
  for (int i = 0; i < 2; ++i) {
    int idx = i * 256 + tid;
    int nr = idx >> 3, kslot = idx & 7;
    short8 v;
#pragma unroll
    for (int j = 0; j < 8; ++j)
      ((unsigned short*)&v)[j] = (unsigned short)bfbits(tile[kslot * 8 + j][nr] * scale);
    *(short8*)&o[(nb + nr) * DIM + kb + kslot * 8] = v;
  }
}

// ---------------- fused: QKV GEMM (blocks 0..255) + edge-bucket fill (blocks 256+) ----
__global__ __launch_bounds__(256) void gemm_fill(
    const float* __restrict__ inp, const unsigned short* __restrict__ Wtb,
    const int* __restrict__ src, const int* __restrict__ dst, int E,
    int* __restrict__ cnt, int* __restrict__ esrc,
    unsigned short* __restrict__ Qb, unsigned short* __restrict__ Kb,
    unsigned short* __restrict__ Vtb) {
  __shared__ __align__(16) short sA[64 * 256];   // 32 KB
  __shared__ __align__(16) short sB[64 * 256];   // 32 KB
  const int tid = threadIdx.x;
  const int b = blockIdx.x;
  if (b >= 256) {                  // fill: slot = atomicAdd(cnt[d]); esrc[d*BCAP+slot]=src
    int e = (b - 256) * 256 + tid;
    if (e < E) {
      int d = dst[e];
      int p = atomicAdd(&cnt[d], 1);
      if (p < BCAP) esrc[d * BCAP + p] = src[e];
    }
    return;
  }
  const int m0 = (b & 63) * 64;
  const int n0 = (b >> 6) * 64;
  // stage A once: f32 -> bf16 during copy (64 rows x 64 slots x 4 f32)
#pragma unroll
  for (int i = 0; i < 16; ++i) {
    int idx = i * 256 + tid;
    int row = idx >> 6, slot = idx & 63;
    float4 v = *(const float4*)&inp[(m0 + row) * DIM + slot * 4];
    uint2 pk = make_uint2(pk_bf16(v.x, v.y), pk_bf16(v.z, v.w));
    int byte = (slot * 8) ^ ((row & 15) << 4);
    *(uint2*)((char*)sA + row * 512 + byte) = pk;
  }
  const int kl = tid & 31, hi = (tid & 63) >> 5, w = tid >> 6;
  const int rw = (w >> 1) * 32, cw = (w & 1) * 32;
  const int arow = rw + kl, brow = cw + kl;
  const int axor = (arow & 15) << 4, bxor = (brow & 15) << 4;
  const char* apA = (const char*)sA + arow * 512;
  const char* apB = (const char*)sB + brow * 512;

#pragma unroll 1
  for (int wsel = 0; wsel < 3; ++wsel) {
    const unsigned short* Wt = Wtb + wsel * 65536;
    __syncthreads();               // prev compute done reading sB (wsel0: none)
#pragma unroll
    for (int i = 0; i < 8; ++i) {
      int idx = i * 256 + tid;
      int row = idx >> 5, slot = idx & 31;
      short8 v = *(const short8*)&Wt[(n0 + row) * DIM + slot * 8];
      int byte = (slot * 16) ^ ((row & 15) << 4);
      *(short8*)((char*)sB + row * 512 + byte) = v;
    }
    __syncthreads();               // sB (and sA on first iter) visible
    f32x16 acc;
#pragma unroll
    for (int r = 0; r < 16; ++r) acc[r] = 0.f;
#pragma unroll
    for (int ks = 0; ks < 16; ++ks) {
      int cb = ks * 32 + hi * 16;
      short8 a = *(const short8*)(apA + (cb ^ axor));
      short8 bfr = *(const short8*)(apB + (cb ^ bxor));
      acc = __builtin_amdgcn_mfma_f32_32x32x16_bf16(a, bfr, acc, 0, 0, 0);
    }
    if (wsel < 2) {
      unsigned short* C = wsel == 0 ? Qb : Kb;
#pragma unroll
      for (int r = 0; r < 16; ++r) {
        int mrow = (r & 3) + 8 * (r >> 2) + 4 * hi;
        C[(m0 + rw + mrow) * DIM + n0 + cw + kl] = (unsigned short)bfbits(acc[r]);
      }
    } else {
      // V: transpose via LDS (sB reused as [64 m][72] ushort tile) -> Vtb[dim][node]
      __syncthreads();             // all waves done reading sB
      unsigned short* tile = (unsigned short*)sB;
#pragma unroll
      for (int r = 0; r < 16; ++r) {
        int mrow = (r & 3) + 8 * (r >> 2) + 4 * hi;
        tile[(rw + mrow) * 72 + cw + kl] = (unsigned short)bfbits(acc[r]);
      }
      __syncthreads();
#pragma unroll
      for (int i = 0; i < 2; ++i) {
        int idx = i * 256 + tid;
        int drow = idx >> 3, nslot = idx & 7;
        short8 v;
#pragma unroll
        for (int j = 0; j < 8; ++j)
          ((unsigned short*)&v)[j] = tile[(nslot * 8 + j) * 72 + drow];
        *(short8*)&Vtb[(n0 + drow) * NN + m0 + nslot * 8] = v;
      }
    }
  }
}

// ---------------- K2 gather from buckets: wave per dst node, ILP-4 ----------------
__global__ __launch_bounds__(256) void gather_k2(
    const unsigned short* __restrict__ Kb, const int* __restrict__ cnt,
    const int* __restrict__ esrc, unsigned short* __restrict__ K2b) {
  int w = threadIdx.x >> 6, lane = threadIdx.x & 63;
  int d = blockIdx.x * 4 + w;
  int n = cnt[d]; n = n > BCAP ? BCAP : n;
  const int* eb = esrc + d * BCAP;
  float a0 = 0, a1 = 0, a2 = 0, a3 = 0;
  int j = 0;
  for (; j + 4 <= n; j += 4) {     // 4 independent load chains in flight
    int s0 = eb[j], s1 = eb[j + 1], s2 = eb[j + 2], s3 = eb[j + 3];
    ushort4 k0 = *(const ushort4*)&Kb[s0 * DIM + lane * 4];
    ushort4 k1 = *(const ushort4*)&Kb[s1 * DIM + lane * 4];
    ushort4 k2 = *(const ushort4*)&Kb[s2 * DIM + lane * 4];
    ushort4 k3 = *(const ushort4*)&Kb[s3 * DIM + lane * 4];
    a0 += bf2f(k0.x) + bf2f(k1.x) + bf2f(k2.x) + bf2f(k3.x);
    a1 += bf2f(k0.y) + bf2f(k1.y) + bf2f(k2.y) + bf2f(k3.y);
    a2 += bf2f(k0.z) + bf2f(k1.z) + bf2f(k2.z) + bf2f(k3.z);
    a3 += bf2f(k0.w) + bf2f(k1.w) + bf2f(k2.w) + bf2f(k3.w);
  }
  for (; j < n; ++j) {
    int s = eb[j];
    ushort4 kv = *(const ushort4*)&Kb[s * DIM + lane * 4];
    a0 += bf2f(kv.x); a1 += bf2f(kv.y); a2 += bf2f(kv.z); a3 += bf2f(kv.w);
  }
  ushort4 o;
  o.x = bfbits(a0); o.y = bfbits(a1); o.z = bfbits(a2); o.w = bfbits(a3);
  *(ushort4*)&K2b[d * DIM + lane * 4] = o;
}

// ---------------- fused MFMA flash attention + merge (r16: barrier-free K-loop) ----
// grid (128 q-blocks, 8 heads); block 512 = 8 waves; ALL waves share the same 32 q
// rows; wave zg owns keys [zg*512, zg*512+512) = 16 subs of 32 keys.
// Key insight: swapped-MFMA A-fragments are per-lane-distinct rows -- no cross-lane
// LDS reuse existed. Load A-frags DIRECTLY from global (L2-resident; each key's
// head-slice = one 64B line fully consumed by the hi-pair). Zero mid-loop barriers;
// waves stream independently; single merge barrier at the end. LDS 35KB -> 4
// blocks/CU = up to 8 waves/SIMD. launch_bounds(512,4): cap 128, spill-proof.
__global__ __launch_bounds__(512, 4) void attn_fused(
    const unsigned short* __restrict__ Qb, const unsigned short* __restrict__ K2b,
    const unsigned short* __restrict__ Vtb, const float* __restrict__ inp,
    unsigned short* __restrict__ Hbf) {
  __shared__ float mz[8][32 * 33];   // 33.8 KB merge buffers
  __shared__ float lbuf[8][32];
  const int tid = threadIdx.x;
  const int lane = tid & 63;
  const int zg = tid >> 6;           // wave id = key-split group 0..7
  const int kl = lane & 31;
  const int hi = lane >> 5;
  const int h = blockIdx.y, hc = h * HDIM;
  const int q = blockIdx.x * 32 + kl;

  short8 qf0 = *(const short8*)&Qb[q * DIM + hc + hi * 8];
  short8 qf1 = *(const short8*)&Qb[q * DIM + hc + 16 + hi * 8];

  // direct A-frag pointers (formulas identical to the proven staged-LDS composition)
  const unsigned short* kp = &K2b[(zg * 512 + kl) * DIM + hc + hi * 8];
  const unsigned short* vp = &Vtb[(hc + kl) * NN + zg * 512 + hi * 8];

  f32x16 o;
#pragma unroll
  for (int r = 0; r < 16; ++r) o[r] = 0.f;
  float lsum = 0.f;

#pragma unroll 2
  for (int sub = 0; sub < 16; ++sub) {
    short8 a0 = *(const short8*)(kp);          // K2 rows: key = base+kl, dims hi*8..
    short8 a1 = *(const short8*)(kp + 16);     // dims 16+hi*8..
    short8 va0 = *(const short8*)(vp);         // V^T rows: dim = kl, keys base+hi*8..
    short8 va1 = *(const short8*)(vp + 16);    // keys base+16+hi*8..
    kp += 32 * DIM; vp += 32;
    f32x16 c;
#pragma unroll
    for (int r = 0; r < 16; ++r) c[r] = 0.f;
    __builtin_amdgcn_s_setprio(1);
    c = __builtin_amdgcn_mfma_f32_32x32x16_bf16(a0, qf0, c, 0, 0, 0);
    c = __builtin_amdgcn_mfma_f32_32x32x16_bf16(a1, qf1, c, 0, 0, 0);
    __builtin_amdgcn_s_setprio(0);
    float p[16];
#pragma unroll
    for (int r = 0; r < 16; ++r) p[r] = EXP2(c[r]);
    {  // scalar tree-sum
      float t0 = (p[0] + p[1]) + (p[2] + p[3]);
      float t1 = (p[4] + p[5]) + (p[6] + p[7]);
      float t2 = (p[8] + p[9]) + (p[10] + p[11]);
      float t3 = (p[12] + p[13]) + (p[14] + p[15]);
      lsum += (t0 + t1) + (t2 + t3);
    }
    unsigned X0 = pk_bf16(p[0], p[1]);
    unsigned Y0 = pk_bf16(p[2], p[3]);
    unsigned Z0 = pk_bf16(p[4], p[5]);
    unsigned W0 = pk_bf16(p[6], p[7]);
    asm volatile("v_permlane32_swap_b32 %0, %1" : "+v"(X0), "+v"(Z0));
    asm volatile("v_permlane32_swap_b32 %0, %1" : "+v"(Y0), "+v"(W0));
    unsigned X1 = pk_bf16(p[8], p[9]);
    unsigned Y1 = pk_bf16(p[10], p[11]);
    unsigned Z1 = pk_bf16(p[12], p[13]);
    unsigned W1 = pk_bf16(p[14], p[15]);
    asm volatile("v_permlane32_swap_b32 %0, %1" : "+v"(X1), "+v"(Z1));
    asm volatile("v_permlane32_swap_b32 %0, %1" : "+v"(Y1), "+v"(W1));
    short8 pb0, pb1;
    ((unsigned*)&pb0)[0] = X0; ((unsigned*)&pb0)[1] = Y0;
    ((unsigned*)&pb0)[2] = Z0; ((unsigned*)&pb0)[3] = W0;
    ((unsigned*)&pb1)[0] = X1; ((unsigned*)&pb1)[1] = Y1;
    ((unsigned*)&pb1)[2] = Z1; ((unsigned*)&pb1)[3] = W1;
    __builtin_amdgcn_s_setprio(1);
    o = __builtin_amdgcn_mfma_f32_32x32x16_bf16(va0, pb0, o, 0, 0, 0);
    o = __builtin_amdgcn_mfma_f32_32x32x16_bf16(va1, pb1, o, 0, 0, 0);
    __builtin_amdgcn_s_setprio(0);
  }

  // single-barrier merge: 8 per-wave partials through LDS
  float lt = lsum + __shfl_xor(lsum, 32);
  float* m = mz[zg];
#pragma unroll
  for (int r = 0; r < 16; ++r) {
    int d = (r & 3) + 8 * (r >> 2) + 4 * hi;
    m[d * 33 + kl] = o[r];
  }
  if (hi == 0) lbuf[zg][kl] = lt;
  __syncthreads();
  if (tid < 256) {
    int ql = tid >> 3;               // 0..31
    int dg = (tid & 7) * 4;          // 0..28
    float s = ((lbuf[0][ql] + lbuf[1][ql]) + (lbuf[2][ql] + lbuf[3][ql])) +
              ((lbuf[4][ql] + lbuf[5][ql]) + (lbuf[6][ql] + lbuf[7][ql]));
    float inv = 1.f / s;
    float acc[4];
#pragma unroll
    for (int i = 0; i < 4; ++i) {
      int off = (dg + i) * 33 + ql;
      acc[i] = ((mz[0][off] + mz[1][off]) + (mz[2][off] + mz[3][off])) +
               ((mz[4][off] + mz[5][off]) + (mz[6][off] + mz[7][off]));
    }
    int qg = blockIdx.x * 32 + ql;
    float4 in4 = *(const float4*)&inp[qg * DIM + hc + dg];
    ushort4 hb;
    hb.x = bfbits(in4.x + acc[0] * inv);
    hb.y = bfbits(in4.y + acc[1] * inv);
    hb.z = bfbits(in4.z + acc[2] * inv);
    hb.w = bfbits(in4.w + acc[3] * inv);
    *(ushort4*)&Hbf[qg * DIM + hc + dg] = hb;
  }
}

// ---------------- final GEMM (bf16 MFMA): out = H + leaky(H @ Wc + bc) ----------------
// Residual H read back from the staged sA tile (bf16) -- no Hf buffer.
__global__ __launch_bounds__(256) void gemm_final_mfma(
    const unsigned short* __restrict__ Hbf, const unsigned short* __restrict__ Wct,
    const float* __restrict__ bc, float* __restrict__ out) {
  __shared__ __align__(16) short sA[64 * 256];
  __shared__ __align__(16) short sB[64 * 256];
  const int tid = threadIdx.x;
  const int m0 = blockIdx.x * 64;
  const int n0 = blockIdx.y * 64;
#pragma unroll
  for (int i = 0; i < 8; ++i) {
    int idx = i * 256 + tid;
    int row = idx >> 5, slot = idx & 31;
    short8 v = *(const short8*)&Hbf[(m0 + row) * DIM + slot * 8];
    int byte = (slot * 16) ^ ((row & 15) << 4);
    *(short8*)((char*)sA + row * 512 + byte) = v;
  }
#pragma unroll
  for (int i = 0; i < 8; ++i) {
    int idx = i * 256 + tid;
    int row = idx >> 5, slot = idx & 31;
    short8 v = *(const short8*)&Wct[(n0 + row) * DIM + slot * 8];
    int byte = (slot * 16) ^ ((row & 15) << 4);
    *(short8*)((char*)sB + row * 512 + byte) = v;
  }
  __syncthreads();
  const int kl = tid & 31, hi = (tid & 63) >> 5, w = tid >> 6;
  const int rw = (w >> 1) * 32, cw = (w & 1) * 32;
  const int arow = rw + kl, brow = cw + kl;
  const int axor = (arow & 15) << 4, bxor = (brow & 15) << 4;
  const char* apA = (const char*)sA + arow * 512;
  const char* apB = (const char*)sB + brow * 512;
  f32x16 acc;
#pragma unroll
  for (int r = 0; r < 16; ++r) acc[r] = 0.f;
#pragma unroll
  for (int ks = 0; ks < 16; ++ks) {
    int cb = ks * 32 + hi * 16;
    short8 a = *(const short8*)(apA + (cb ^ axor));
    short8 b = *(const short8*)(apB + (cb ^ bxor));
    acc = __builtin_amdgcn_mfma_f32_32x32x16_bf16(a, b, acc, 0, 0, 0);
  }
#pragma unroll
  for (int r = 0; r < 16; ++r) {
    int mrow = (r & 3) + 8 * (r >> 2) + 4 * hi;
    int lrow = rw + mrow;
    int node = m0 + lrow, col = n0 + cw + kl;
    float x = acc[r] + bc[col];
    x = x > 0.f ? x : LEAKY * x;
    // residual from staged sA (Hbf tile, swizzle-consistent ushort read)
    unsigned short hr = *(const unsigned short*)(
        (const char*)sA + lrow * 512 + ((col * 2) ^ ((lrow & 15) << 4)));
    out[node * DIM + col] = bf2f(hr) + x;
  }
}

extern "C" void kernel_launch(void* const* d_in, const int* in_sizes, int n_in,
                              void* d_out, int out_size, void* d_ws, size_t ws_size,
                              hipStream_t stream) {
  const float* inp = (const float*)d_in[0];
  const int* src   = (const int*)d_in[1];
  const int* dst   = (const int*)d_in[2];
  const float* WQ  = (const float*)d_in[3];
  const float* WK  = (const float*)d_in[4];
  const float* WV  = (const float*)d_in[5];
  const float* Wc  = (const float*)d_in[6];
  const float* bc  = (const float*)d_in[7];
  float* out = (float*)d_out;
  const int E = in_sizes[1];

  // ws layout (~12.6 MB):
  char* ws = (char*)d_ws;
  unsigned short* Qb  = (unsigned short*)(ws);                      // 2 MB
  unsigned short* Kb  = (unsigned short*)(ws + 2  * 1024 * 1024);   // 2 MB
  unsigned short* Vtb = (unsigned short*)(ws + 4  * 1024 * 1024);   // 2 MB
  unsigned short* K2b = (unsigned short*)(ws + 6  * 1024 * 1024);   // 2 MB
  unsigned short* Wtb = (unsigned short*)(ws + 8  * 1024 * 1024);   // 512 KB
  unsigned short* Hbf = (unsigned short*)(ws + 8 * 1024 * 1024 + 524288);   // 2 MB
  int* cnt            = (int*)(ws + 10 * 1024 * 1024 + 524288);     // 16 KB
  int* esrc           = (int*)(ws + 10 * 1024 * 1024 + 540672);     // 2 MB (4096 x 128)

  const int fillBlocks = (E + 255) / 256;
  convert_w<<<dim3(16, 4), 256, 0, stream>>>(WQ, WK, WV, Wc, Wtb, cnt);
  gemm_fill<<<256 + fillBlocks, 256, 0, stream>>>(inp, Wtb, src, dst, E, cnt, esrc,
                                                  Qb, Kb, Vtb);
  gather_k2<<<NN / 4, 256, 0, stream>>>(Kb, cnt, esrc, K2b);
  attn_fused<<<dim3(128, 8), 512, 0, stream>>>(Qb, K2b, Vtb, inp, Hbf);
  gemm_final_mfma<<<dim3(64, 4), 256, 0, stream>>>(Hbf, Wtb + 3 * 65536, bc, out);
}

// Round 17
// 79.752 us; speedup vs baseline: 1.2677x; 1.2677x over previous
//
#include <hip/hip_runtime.h>
#include <hip/hip_bf16.h>
#include <math.h>

#define DIM 256
#define HDIM 32
#define NN 4096
#define NM (NN * DIM)
// (1/sqrt(256)) * log2(e) -- folded into WQ so scores are in exp2 domain
#define PREF 0.09016844005555896f
#define LEAKY 0.2f
#define BCAP 128   // edge-bucket capacity per dst (Poisson(32): P(deg>128) ~ 0)

typedef __attribute__((ext_vector_type(8))) short short8;
typedef __attribute__((ext_vector_type(16))) float f32x16;

#if __has_builtin(__builtin_amdgcn_exp2f)
#define EXP2(x) __builtin_amdgcn_exp2f(x)   // raw v_exp_f32: scores bounded, no fixups needed
#else
#define EXP2(x) exp2f(x)
#endif

static __device__ __forceinline__ unsigned bfbits(float x) {
  unsigned u = __float_as_uint(x);
  return (u + 0x7fffu + ((u >> 16) & 1u)) >> 16;   // RNE f32->bf16 bits
}
static __device__ __forceinline__ float bf2f(unsigned short b) {
  return __uint_as_float(((unsigned)b) << 16);
}
static __device__ __forceinline__ unsigned pk_bf16(float lo, float hi) {
  __hip_bfloat162 t = __float22bfloat162_rn(make_float2(lo, hi));  // v_cvt_pk_bf16_f32
  return *(unsigned*)&t;
}

// ---- convert: Wtb[w][n][k] = bf16(W_w[k][n]*scale); grid (16,4); y==0 blocks zero cnt
__global__ __launch_bounds__(256) void convert_w(
    const float* __restrict__ W0, const float* __restrict__ W1,
    const float* __restrict__ W2, const float* __restrict__ W3,
    unsigned short* __restrict__ Wtb, int* __restrict__ cnt) {
  const int tid = threadIdx.x;
  if (blockIdx.y == 0) cnt[blockIdx.x * 256 + tid] = 0;   // 16x256 = 4096 ints
  __shared__ float tile[64][68];
  const int wsel = blockIdx.y;
  const float* W = wsel == 0 ? W0 : (wsel == 1 ? W1 : (wsel == 2 ? W2 : W3));
  const float scale = wsel == 0 ? PREF : 1.f;
  const int kb = (blockIdx.x & 3) * 64, nb = (blockIdx.x >> 2) * 64;
#pragma unroll
  for (int i = 0; i < 4; ++i) {
    int idx = i * 256 + tid;
    int kr = idx >> 4, ns = idx & 15;
    float4 v = *(const float4*)&W[(kb + kr) * DIM + nb + ns * 4];
    tile[kr][ns * 4 + 0] = v.x; tile[kr][ns * 4 + 1] = v.y;
    tile[kr][ns * 4 + 2] = v.z; tile[kr][ns * 4 + 3] = v.w;
  }
  __syncthreads();
  unsigned short* o = Wtb + wsel * 65536;
#pragma unroll
  for (int i = 0; i < 2; ++i) {
    int idx = i * 256 + tid;
    int nr = idx >> 3, kslot = idx & 7;
    short8 v;
#pragma unroll
    for (int j = 0; j < 8; ++j)
      ((unsigned short*)&v)[j] = (unsigned short)bfbits(tile[kslot * 8 + j][nr] * scale);
    *(short8*)&o[(nb + nr) * DIM + kb + kslot * 8] = v;
  }
}

// ---------------- fused: QKV GEMM (blocks 0..255) + edge-bucket fill (blocks 256+) ----
__global__ __launch_bounds__(256) void gemm_fill(
    const float* __restrict__ inp, const unsigned short* __restrict__ Wtb,
    const int* __restrict__ src, const int* __restrict__ dst, int E,
    int* __restrict__ cnt, int* __restrict__ esrc,
    unsigned short* __restrict__ Qb, unsigned short* __restrict__ Kb,
    unsigned short* __restrict__ Vtb) {
  __shared__ __align__(16) short sA[64 * 256];   // 32 KB
  __shared__ __align__(16) short sB[64 * 256];   // 32 KB
  const int tid = threadIdx.x;
  const int b = blockIdx.x;
  if (b >= 256) {                  // fill: slot = atomicAdd(cnt[d]); esrc[d*BCAP+slot]=src
    int e = (b - 256) * 256 + tid;
    if (e < E) {
      int d = dst[e];
      int p = atomicAdd(&cnt[d], 1);
      if (p < BCAP) esrc[d * BCAP + p] = src[e];
    }
    return;
  }
  const int m0 = (b & 63) * 64;
  const int n0 = (b >> 6) * 64;
  // stage A once: f32 -> bf16 during copy (64 rows x 64 slots x 4 f32)
#pragma unroll
  for (int i = 0; i < 16; ++i) {
    int idx = i * 256 + tid;
    int row = idx >> 6, slot = idx & 63;
    float4 v = *(const float4*)&inp[(m0 + row) * DIM + slot * 4];
    uint2 pk = make_uint2(pk_bf16(v.x, v.y), pk_bf16(v.z, v.w));
    int byte = (slot * 8) ^ ((row & 15) << 4);
    *(uint2*)((char*)sA + row * 512 + byte) = pk;
  }
  const int kl = tid & 31, hi = (tid & 63) >> 5, w = tid >> 6;
  const int rw = (w >> 1) * 32, cw = (w & 1) * 32;
  const int arow = rw + kl, brow = cw + kl;
  const int axor = (arow & 15) << 4, bxor = (brow & 15) << 4;
  const char* apA = (const char*)sA + arow * 512;
  const char* apB = (const char*)sB + brow * 512;

#pragma unroll 1
  for (int wsel = 0; wsel < 3; ++wsel) {
    const unsigned short* Wt = Wtb + wsel * 65536;
    __syncthreads();               // prev compute done reading sB (wsel0: none)
#pragma unroll
    for (int i = 0; i < 8; ++i) {
      int idx = i * 256 + tid;
      int row = idx >> 5, slot = idx & 31;
      short8 v = *(const short8*)&Wt[(n0 + row) * DIM + slot * 8];
      int byte = (slot * 16) ^ ((row & 15) << 4);
      *(short8*)((char*)sB + row * 512 + byte) = v;
    }
    __syncthreads();               // sB (and sA on first iter) visible
    f32x16 acc;
#pragma unroll
    for (int r = 0; r < 16; ++r) acc[r] = 0.f;
#pragma unroll
    for (int ks = 0; ks < 16; ++ks) {
      int cb = ks * 32 + hi * 16;
      short8 a = *(const short8*)(apA + (cb ^ axor));
      short8 bfr = *(const short8*)(apB + (cb ^ bxor));
      acc = __builtin_amdgcn_mfma_f32_32x32x16_bf16(a, bfr, acc, 0, 0, 0);
    }
    if (wsel < 2) {
      unsigned short* C = wsel == 0 ? Qb : Kb;
#pragma unroll
      for (int r = 0; r < 16; ++r) {
        int mrow = (r & 3) + 8 * (r >> 2) + 4 * hi;
        C[(m0 + rw + mrow) * DIM + n0 + cw + kl] = (unsigned short)bfbits(acc[r]);
      }
    } else {
      // V: transpose via LDS (sB reused as [64 m][72] ushort tile) -> Vtb[dim][node]
      __syncthreads();             // all waves done reading sB
      unsigned short* tile = (unsigned short*)sB;
#pragma unroll
      for (int r = 0; r < 16; ++r) {
        int mrow = (r & 3) + 8 * (r >> 2) + 4 * hi;
        tile[(rw + mrow) * 72 + cw + kl] = (unsigned short)bfbits(acc[r]);
      }
      __syncthreads();
#pragma unroll
      for (int i = 0; i < 2; ++i) {
        int idx = i * 256 + tid;
        int drow = idx >> 3, nslot = idx & 7;
        short8 v;
#pragma unroll
        for (int j = 0; j < 8; ++j)
          ((unsigned short*)&v)[j] = tile[(nslot * 8 + j) * 72 + drow];
        *(short8*)&Vtb[(n0 + drow) * NN + m0 + nslot * 8] = v;
      }
    }
  }
}

// ---------------- K2 gather from buckets: wave per dst node, ILP-4 ----------------
__global__ __launch_bounds__(256) void gather_k2(
    const unsigned short* __restrict__ Kb, const int* __restrict__ cnt,
    const int* __restrict__ esrc, unsigned short* __restrict__ K2b) {
  int w = threadIdx.x >> 6, lane = threadIdx.x & 63;
  int d = blockIdx.x * 4 + w;
  int n = cnt[d]; n = n > BCAP ? BCAP : n;
  const int* eb = esrc + d * BCAP;
  float a0 = 0, a1 = 0, a2 = 0, a3 = 0;
  int j = 0;
  for (; j + 4 <= n; j += 4) {     // 4 independent load chains in flight
    int s0 = eb[j], s1 = eb[j + 1], s2 = eb[j + 2], s3 = eb[j + 3];
    ushort4 k0 = *(const ushort4*)&Kb[s0 * DIM + lane * 4];
    ushort4 k1 = *(const ushort4*)&Kb[s1 * DIM + lane * 4];
    ushort4 k2 = *(const ushort4*)&Kb[s2 * DIM + lane * 4];
    ushort4 k3 = *(const ushort4*)&Kb[s3 * DIM + lane * 4];
    a0 += bf2f(k0.x) + bf2f(k1.x) + bf2f(k2.x) + bf2f(k3.x);
    a1 += bf2f(k0.y) + bf2f(k1.y) + bf2f(k2.y) + bf2f(k3.y);
    a2 += bf2f(k0.z) + bf2f(k1.z) + bf2f(k2.z) + bf2f(k3.z);
    a3 += bf2f(k0.w) + bf2f(k1.w) + bf2f(k2.w) + bf2f(k3.w);
  }
  for (; j < n; ++j) {
    int s = eb[j];
    ushort4 kv = *(const ushort4*)&Kb[s * DIM + lane * 4];
    a0 += bf2f(kv.x); a1 += bf2f(kv.y); a2 += bf2f(kv.z); a3 += bf2f(kv.w);
  }
  ushort4 o;
  o.x = bfbits(a0); o.y = bfbits(a1); o.z = bfbits(a2); o.w = bfbits(a3);
  *(ushort4*)&K2b[d * DIM + lane * 4] = o;
}

// ---- per-tile compute (64-key tile, 2 subs): QK^T -> exp2 -> pack/permlane -> PV ----
static __device__ __forceinline__ void compute_tile64(
    const short* __restrict__ lk, const short* __restrict__ lv, int kl, int hi,
    short8 qf0, short8 qf1, const f32x16& zc, f32x16& o, float& lsum) {
#pragma unroll
  for (int sub = 0; sub < 2; ++sub) {
    const int base = sub * 32;
    short8 a0 = *(const short8*)&lk[(base + kl) * 40 + hi * 8];
    short8 a1 = *(const short8*)&lk[(base + kl) * 40 + 16 + hi * 8];
    __builtin_amdgcn_s_setprio(1);
    f32x16 c = __builtin_amdgcn_mfma_f32_32x32x16_bf16(a0, qf0, zc, 0, 0, 0);
    c = __builtin_amdgcn_mfma_f32_32x32x16_bf16(a1, qf1, c, 0, 0, 0);
    __builtin_amdgcn_s_setprio(0);
    float p[16];
#pragma unroll
    for (int r = 0; r < 16; ++r) p[r] = EXP2(c[r]);
    {  // scalar tree-sum
      float t0 = (p[0] + p[1]) + (p[2] + p[3]);
      float t1 = (p[4] + p[5]) + (p[6] + p[7]);
      float t2 = (p[8] + p[9]) + (p[10] + p[11]);
      float t3 = (p[12] + p[13]) + (p[14] + p[15]);
      lsum += (t0 + t1) + (t2 + t3);
    }
    unsigned X0 = pk_bf16(p[0], p[1]);
    unsigned Y0 = pk_bf16(p[2], p[3]);
    unsigned Z0 = pk_bf16(p[4], p[5]);
    unsigned W0 = pk_bf16(p[6], p[7]);
    asm volatile("v_permlane32_swap_b32 %0, %1" : "+v"(X0), "+v"(Z0));
    asm volatile("v_permlane32_swap_b32 %0, %1" : "+v"(Y0), "+v"(W0));
    unsigned X1 = pk_bf16(p[8], p[9]);
    unsigned Y1 = pk_bf16(p[10], p[11]);
    unsigned Z1 = pk_bf16(p[12], p[13]);
    unsigned W1 = pk_bf16(p[14], p[15]);
    asm volatile("v_permlane32_swap_b32 %0, %1" : "+v"(X1), "+v"(Z1));
    asm volatile("v_permlane32_swap_b32 %0, %1" : "+v"(Y1), "+v"(W1));
    short8 pb0, pb1;
    ((unsigned*)&pb0)[0] = X0; ((unsigned*)&pb0)[1] = Y0;
    ((unsigned*)&pb0)[2] = Z0; ((unsigned*)&pb0)[3] = W0;
    ((unsigned*)&pb1)[0] = X1; ((unsigned*)&pb1)[1] = Y1;
    ((unsigned*)&pb1)[2] = Z1; ((unsigned*)&pb1)[3] = W1;
    short8 va0 = *(const short8*)&lv[kl * 72 + base + hi * 8];
    short8 va1 = *(const short8*)&lv[kl * 72 + base + 16 + hi * 8];
    __builtin_amdgcn_s_setprio(1);
    o = __builtin_amdgcn_mfma_f32_32x32x16_bf16(va0, pb0, o, 0, 0, 0);
    o = __builtin_amdgcn_mfma_f32_32x32x16_bf16(va1, pb1, o, 0, 0, 0);
    __builtin_amdgcn_s_setprio(0);
  }
}

// ---------------- MFMA flash attention, key-split across blocks ----------------
// r17: grid (64 qg, 8 heads, 2 key-halves); block 512 = 2 q-waves x 4 z-groups,
// each zg 512 keys (8 tiles of 64). 1024 blocks x 8 waves = 8192 waves = 8/SIMD;
// LDS 39.9KB x 4 blocks/CU = 159.7KB (fits). Identical inner code to r14 (proven
// VGPR 64, no spill, launch_bounds(512,4) cap 128). Partials to Op/Lp via PLAIN
// coalesced stores (r2 lesson: no atomics); merge_h combines the 2 halves.
__global__ __launch_bounds__(512, 4) void attn_fused(
    const unsigned short* __restrict__ Qb, const unsigned short* __restrict__ K2b,
    const unsigned short* __restrict__ Vtb,
    float* __restrict__ Op, float* __restrict__ Lp) {
  __shared__ __align__(16) char smem[38912];   // 4 x (lk[64][40] | lv[32][72]) shorts
  __shared__ float lbuf[4][64];
  const int tid = threadIdx.x;
  const int lane = tid & 63;
  const int wid = tid >> 6;
  const int qw = wid & 1;
  const int zg = wid >> 1;        // 0..3
  const int kl = lane & 31;
  const int hi = lane >> 5;
  const int gtid = tid & 127;
  const int h = blockIdx.y, hc = h * HDIM;
  const int zhalf = blockIdx.z;
  const int q_local = qw * 32 + kl;
  const int q = blockIdx.x * 64 + q_local;
  const int ks0 = zhalf * 2048 + zg * 512;

  short* lk = (short*)smem + zg * 4864;            // [64][40]
  short* lv = (short*)smem + zg * 4864 + 2560;     // [32][72]

  const int kkey = gtid >> 1, kslot = gtid & 1;    // K: 2 thr/key
  const int vdim = gtid >> 3, vslot = gtid & 7;    // V: dims vdim, vdim+16
  const unsigned short* kg = &K2b[(ks0 + kkey) * DIM + hc + kslot * 16];
  const unsigned short* vg = &Vtb[(hc + vdim) * NN + ks0 + vslot * 8];
  short* lkw = lk + kkey * 40 + kslot * 16;
  short* lvw = lv + vdim * 72 + vslot * 8;

#define LOADKV(KR, VR)                                                      \
  do {                                                                      \
    KR[0] = *(const short8*)(kg);                                           \
    KR[1] = *(const short8*)(kg + 8);                                       \
    VR[0] = *(const short8*)(vg);                                           \
    VR[1] = *(const short8*)(vg + 16 * NN);                                 \
    kg += 64 * DIM; vg += 64;                                               \
  } while (0)
#define STOREKV(KR, VR)                                                     \
  do {                                                                      \
    *(short8*)(lkw) = KR[0];                                                \
    *(short8*)(lkw + 8) = KR[1];                                            \
    *(short8*)(lvw) = VR[0];                                                \
    *(short8*)(lvw + 16 * 72) = VR[1];                                      \
  } while (0)

  short8 qf0 = *(const short8*)&Qb[q * DIM + hc + hi * 8];
  short8 qf1 = *(const short8*)&Qb[q * DIM + hc + 16 + hi * 8];

  f32x16 zc;
#pragma unroll
  for (int r = 0; r < 16; ++r) zc[r] = 0.f;
  f32x16 o = zc;
  float lsum = 0.f;

  short8 kr[2], vr[2];
  LOADKV(kr, vr);
#pragma unroll 1
  for (int t = 0; t < 8; ++t) {
    __syncthreads();                 // all waves done computing previous tile
    STOREKV(kr, vr);                 // (waits on this tile's loads)
    __syncthreads();                 // tile t visible
    if (t < 7) LOADKV(kr, vr);       // issue next tile's loads; land during compute
    compute_tile64(lk, lv, kl, hi, qf0, qf1, zc, o, lsum);
  }
#undef LOADKV
#undef STOREKV

  // in-block merge of 4 z-groups -> PLAIN partial stores (Op f32, Lp f32)
  float lt = lsum + __shfl_xor(lsum, 32);
  __syncthreads();
  float* mz = (float*)smem + zg * 2208;            // [32 dims][69 q] per group
#pragma unroll
  for (int r = 0; r < 16; ++r) {
    int d = (r & 3) + 8 * (r >> 2) + 4 * hi;
    mz[d * 69 + q_local] = o[r];
  }
  if (hi == 0) lbuf[zg][q_local] = lt;
  __syncthreads();
  {
    int ql = tid >> 3;               // 0..63
    int dg = (tid & 7) * 4;          // 0..28
    float s = (lbuf[0][ql] + lbuf[1][ql]) + (lbuf[2][ql] + lbuf[3][ql]);
    const float* mb = (const float*)smem;
    float acc[4];
#pragma unroll
    for (int i = 0; i < 4; ++i) {
      int off = (dg + i) * 69 + ql;
      acc[i] = (mb[off] + mb[2208 + off]) + (mb[4416 + off] + mb[6624 + off]);
    }
    int qg = blockIdx.x * 64 + ql;
    *(float4*)&Op[zhalf * NM + qg * DIM + hc + dg] =
        make_float4(acc[0], acc[1], acc[2], acc[3]);
    if ((tid & 7) == 0) Lp[(zhalf * 8 + h) * NN + qg] = s;
  }
}

// ---------------- merge halves: Hbf = bf16(inp + (Op0+Op1) / (L0+L1)) ----------------
__global__ __launch_bounds__(256) void merge_h(
    const float* __restrict__ inp, const float* __restrict__ Op,
    const float* __restrict__ Lp, unsigned short* __restrict__ Hbf) {
  int i = (blockIdx.x * 256 + threadIdx.x) * 4;
  int q = i >> 8;
  int hh = (i & 255) >> 5;
  float inv = 1.f / (Lp[hh * NN + q] + Lp[(8 + hh) * NN + q]);
  float4 a = *(const float4*)&Op[i];
  float4 b = *(const float4*)&Op[NM + i];
  float4 in4 = *(const float4*)&inp[i];
  ushort4 hb;
  hb.x = bfbits(in4.x + (a.x + b.x) * inv);
  hb.y = bfbits(in4.y + (a.y + b.y) * inv);
  hb.z = bfbits(in4.z + (a.z + b.z) * inv);
  hb.w = bfbits(in4.w + (a.w + b.w) * inv);
  *(ushort4*)&Hbf[i] = hb;
}

// ---------------- final GEMM (bf16 MFMA): out = H + leaky(H @ Wc + bc) ----------------
// Residual H read back from the staged sA tile (bf16) -- no Hf buffer.
__global__ __launch_bounds__(256) void gemm_final_mfma(
    const unsigned short* __restrict__ Hbf, const unsigned short* __restrict__ Wct,
    const float* __restrict__ bc, float* __restrict__ out) {
  __shared__ __align__(16) short sA[64 * 256];
  __shared__ __align__(16) short sB[64 * 256];
  const int tid = threadIdx.x;
  const int m0 = blockIdx.x * 64;
  const int n0 = blockIdx.y * 64;
#pragma unroll
  for (int i = 0; i < 8; ++i) {
    int idx = i * 256 + tid;
    int row = idx >> 5, slot = idx & 31;
    short8 v = *(const short8*)&Hbf[(m0 + row) * DIM + slot * 8];
    int byte = (slot * 16) ^ ((row & 15) << 4);
    *(short8*)((char*)sA + row * 512 + byte) = v;
  }
#pragma unroll
  for (int i = 0; i < 8; ++i) {
    int idx = i * 256 + tid;
    int row = idx >> 5, slot = idx & 31;
    short8 v = *(const short8*)&Wct[(n0 + row) * DIM + slot * 8];
    int byte = (slot * 16) ^ ((row & 15) << 4);
    *(short8*)((char*)sB + row * 512 + byte) = v;
  }
  __syncthreads();
  const int kl = tid & 31, hi = (tid & 63) >> 5, w = tid >> 6;
  const int rw = (w >> 1) * 32, cw = (w & 1) * 32;
  const int arow = rw + kl, brow = cw + kl;
  const int axor = (arow & 15) << 4, bxor = (brow & 15) << 4;
  const char* apA = (const char*)sA + arow * 512;
  const char* apB = (const char*)sB + brow * 512;
  f32x16 acc;
#pragma unroll
  for (int r = 0; r < 16; ++r) acc[r] = 0.f;
#pragma unroll
  for (int ks = 0; ks < 16; ++ks) {
    int cb = ks * 32 + hi * 16;
    short8 a = *(const short8*)(apA + (cb ^ axor));
    short8 b = *(const short8*)(apB + (cb ^ bxor));
    acc = __builtin_amdgcn_mfma_f32_32x32x16_bf16(a, b, acc, 0, 0, 0);
  }
#pragma unroll
  for (int r = 0; r < 16; ++r) {
    int mrow = (r & 3) + 8 * (r >> 2) + 4 * hi;
    int lrow = rw + mrow;
    int node = m0 + lrow, col = n0 + cw + kl;
    float x = acc[r] + bc[col];
    x = x > 0.f ? x : LEAKY * x;
    // residual from staged sA (Hbf tile, swizzle-consistent ushort read)
    unsigned short hr = *(const unsigned short*)(
        (const char*)sA + lrow * 512 + ((col * 2) ^ ((lrow & 15) << 4)));
    out[node * DIM + col] = bf2f(hr) + x;
  }
}

extern "C" void kernel_launch(void* const* d_in, const int* in_sizes, int n_in,
                              void* d_out, int out_size, void* d_ws, size_t ws_size,
                              hipStream_t stream) {
  const float* inp = (const float*)d_in[0];
  const int* src   = (const int*)d_in[1];
  const int* dst   = (const int*)d_in[2];
  const float* WQ  = (const float*)d_in[3];
  const float* WK  = (const float*)d_in[4];
  const float* WV  = (const float*)d_in[5];
  const float* Wc  = (const float*)d_in[6];
  const float* bc  = (const float*)d_in[7];
  float* out = (float*)d_out;
  const int E = in_sizes[1];

  // ws layout (~21 MB):
  char* ws = (char*)d_ws;
  unsigned short* Qb  = (unsigned short*)(ws);                      // 2 MB
  unsigned short* Kb  = (unsigned short*)(ws + 2  * 1024 * 1024);   // 2 MB
  unsigned short* Vtb = (unsigned short*)(ws + 4  * 1024 * 1024);   // 2 MB
  unsigned short* K2b = (unsigned short*)(ws + 6  * 1024 * 1024);   // 2 MB
  unsigned short* Wtb = (unsigned short*)(ws + 8  * 1024 * 1024);   // 512 KB
  unsigned short* Hbf = (unsigned short*)(ws + 8 * 1024 * 1024 + 524288);   // 2 MB
  int* cnt            = (int*)(ws + 10 * 1024 * 1024 + 524288);     // 16 KB
  int* esrc           = (int*)(ws + 10 * 1024 * 1024 + 540672);     // 2 MB (4096 x 128)
  float* Op           = (float*)(ws + 12 * 1024 * 1024 + 540672 + 16384);  // 8 MB
  float* Lp           = (float*)(ws + 20 * 1024 * 1024 + 540672 + 16384);  // 256 KB

  const int fillBlocks = (E + 255) / 256;
  convert_w<<<dim3(16, 4), 256, 0, stream>>>(WQ, WK, WV, Wc, Wtb, cnt);
  gemm_fill<<<256 + fillBlocks, 256, 0, stream>>>(inp, Wtb, src, dst, E, cnt, esrc,
                                                  Qb, Kb, Vtb);
  gather_k2<<<NN / 4, 256, 0, stream>>>(Kb, cnt, esrc, K2b);
  attn_fused<<<dim3(64, 8, 2), 512, 0, stream>>>(Qb, K2b, Vtb, Op, Lp);
  merge_h<<<NM / 1024, 256, 0, stream>>>(inp, Op, Lp, Hbf);
  gemm_final_mfma<<<dim3(64, 4), 256, 0, stream>>>(Hbf, Wtb + 3 * 65536, bc, out);
}

// Round 18
// 75.868 us; speedup vs baseline: 1.3326x; 1.0512x over previous
//
#include <hip/hip_runtime.h>
#include <hip/hip_bf16.h>
#include <math.h>

#define DIM 256
#define HDIM 32
#define NN 4096
#define NM (NN * DIM)
// (1/sqrt(256)) * log2(e) -- folded into WQ so scores are in exp2 domain
#define PREF 0.09016844005555896f
#define LEAKY 0.2f
#define BCAP 128   // edge-bucket capacity per dst (Poisson(32): P(deg>128) ~ 0)

typedef __attribute__((ext_vector_type(8))) short short8;
typedef __attribute__((ext_vector_type(16))) float f32x16;

#if __has_builtin(__builtin_amdgcn_exp2f)
#define EXP2(x) __builtin_amdgcn_exp2f(x)   // raw v_exp_f32: scores bounded, no fixups needed
#else
#define EXP2(x) exp2f(x)
#endif

static __device__ __forceinline__ unsigned bfbits(float x) {
  unsigned u = __float_as_uint(x);
  return (u + 0x7fffu + ((u >> 16) & 1u)) >> 16;   // RNE f32->bf16 bits
}
static __device__ __forceinline__ float bf2f(unsigned short b) {
  return __uint_as_float(((unsigned)b) << 16);
}
static __device__ __forceinline__ unsigned pk_bf16(float lo, float hi) {
  __hip_bfloat162 t = __float22bfloat162_rn(make_float2(lo, hi));  // v_cvt_pk_bf16_f32
  return *(unsigned*)&t;
}

// ---- convert: Wtb[w][n][k] = bf16(W_w[k][n]*scale); grid (16,4); y==0 blocks zero cnt
__global__ __launch_bounds__(256) void convert_w(
    const float* __restrict__ W0, const float* __restrict__ W1,
    const float* __restrict__ W2, const float* __restrict__ W3,
    unsigned short* __restrict__ Wtb, int* __restrict__ cnt) {
  const int tid = threadIdx.x;
  if (blockIdx.y == 0) cnt[blockIdx.x * 256 + tid] = 0;   // 16x256 = 4096 ints
  __shared__ float tile[64][68];
  const int wsel = blockIdx.y;
  const float* W = wsel == 0 ? W0 : (wsel == 1 ? W1 : (wsel == 2 ? W2 : W3));
  const float scale = wsel == 0 ? PREF : 1.f;
  const int kb = (blockIdx.x & 3) * 64, nb = (blockIdx.x >> 2) * 64;
#pragma unroll
  for (int i = 0; i < 4; ++i) {
    int idx = i * 256 + tid;
    int kr = idx >> 4, ns = idx & 15;
    float4 v = *(const float4*)&W[(kb + kr) * DIM + nb + ns * 4];
    tile[kr][ns * 4 + 0] = v.x; tile[kr][ns * 4 + 1] = v.y;
    tile[kr][ns * 4 + 2] = v.z; tile[kr][ns * 4 + 3] = v.w;
  }
  __syncthreads();
  unsigned short* o = Wtb + wsel * 65536;
#pragma unroll
  for (int i = 0; i < 2; ++i) {
    int idx = i * 256 + tid;
    int nr = idx >> 3, kslot = idx & 7;
    short8 v;
#pragma unroll
    for (int j = 0; j < 8; ++j)
      ((unsigned short*)&v)[j] = (unsigned short)bfbits(tile[kslot * 8 + j][nr] * scale);
    *(short8*)&o[(nb + nr) * DIM + kb + kslot * 8] = v;
  }
}

// ---------------- fused: QKV GEMM (blocks 0..255) + edge-bucket fill (blocks 256+) ----
__global__ __launch_bounds__(256) void gemm_fill(
    const float* __restrict__ inp, const unsigned short* __restrict__ Wtb,
    const int* __restrict__ src, const int* __restrict__ dst, int E,
    int* __restrict__ cnt, int* __restrict__ esrc,
    unsigned short* __restrict__ Qb, unsigned short* __restrict__ Kb,
    unsigned short* __restrict__ Vtb) {
  __shared__ __align__(16) short sA[64 * 256];   // 32 KB
  __shared__ __align__(16) short sB[64 * 256];   // 32 KB
  const int tid = threadIdx.x;
  const int b = blockIdx.x;
  if (b >= 256) {                  // fill: slot = atomicAdd(cnt[d]); esrc[d*BCAP+slot]=src
    int e = (b - 256) * 256 + tid;
    if (e < E) {
      int d = dst[e];
      int p = atomicAdd(&cnt[d], 1);
      if (p < BCAP) esrc[d * BCAP + p] = src[e];
    }
    return;
  }
  const int m0 = (b & 63) * 64;
  const int n0 = (b >> 6) * 64;
  // stage A once: f32 -> bf16 during copy (64 rows x 64 slots x 4 f32)
#pragma unroll
  for (int i = 0; i < 16; ++i) {
    int idx = i * 256 + tid;
    int row = idx >> 6, slot = idx & 63;
    float4 v = *(const float4*)&inp[(m0 + row) * DIM + slot * 4];
    uint2 pk = make_uint2(pk_bf16(v.x, v.y), pk_bf16(v.z, v.w));
    int byte = (slot * 8) ^ ((row & 15) << 4);
    *(uint2*)((char*)sA + row * 512 + byte) = pk;
  }
  const int kl = tid & 31, hi = (tid & 63) >> 5, w = tid >> 6;
  const int rw = (w >> 1) * 32, cw = (w & 1) * 32;
  const int arow = rw + kl, brow = cw + kl;
  const int axor = (arow & 15) << 4, bxor = (brow & 15) << 4;
  const char* apA = (const char*)sA + arow * 512;
  const char* apB = (const char*)sB + brow * 512;

#pragma unroll 1
  for (int wsel = 0; wsel < 3; ++wsel) {
    const unsigned short* Wt = Wtb + wsel * 65536;
    __syncthreads();               // prev compute done reading sB (wsel0: none)
#pragma unroll
    for (int i = 0; i < 8; ++i) {
      int idx = i * 256 + tid;
      int row = idx >> 5, slot = idx & 31;
      short8 v = *(const short8*)&Wt[(n0 + row) * DIM + slot * 8];
      int byte = (slot * 16) ^ ((row & 15) << 4);
      *(short8*)((char*)sB + row * 512 + byte) = v;
    }
    __syncthreads();               // sB (and sA on first iter) visible
    f32x16 acc;
#pragma unroll
    for (int r = 0; r < 16; ++r) acc[r] = 0.f;
#pragma unroll
    for (int ks = 0; ks < 16; ++ks) {
      int cb = ks * 32 + hi * 16;
      short8 a = *(const short8*)(apA + (cb ^ axor));
      short8 bfr = *(const short8*)(apB + (cb ^ bxor));
      acc = __builtin_amdgcn_mfma_f32_32x32x16_bf16(a, bfr, acc, 0, 0, 0);
    }
    if (wsel < 2) {
      unsigned short* C = wsel == 0 ? Qb : Kb;
#pragma unroll
      for (int r = 0; r < 16; ++r) {
        int mrow = (r & 3) + 8 * (r >> 2) + 4 * hi;
        C[(m0 + rw + mrow) * DIM + n0 + cw + kl] = (unsigned short)bfbits(acc[r]);
      }
    } else {
      // V: transpose via LDS (sB reused as [64 m][72] ushort tile) -> Vtb[dim][node]
      __syncthreads();             // all waves done reading sB
      unsigned short* tile = (unsigned short*)sB;
#pragma unroll
      for (int r = 0; r < 16; ++r) {
        int mrow = (r & 3) + 8 * (r >> 2) + 4 * hi;
        tile[(rw + mrow) * 72 + cw + kl] = (unsigned short)bfbits(acc[r]);
      }
      __syncthreads();
#pragma unroll
      for (int i = 0; i < 2; ++i) {
        int idx = i * 256 + tid;
        int drow = idx >> 3, nslot = idx & 7;
        short8 v;
#pragma unroll
        for (int j = 0; j < 8; ++j)
          ((unsigned short*)&v)[j] = tile[(nslot * 8 + j) * 72 + drow];
        *(short8*)&Vtb[(n0 + drow) * NN + m0 + nslot * 8] = v;
      }
    }
  }
}

// ---------------- K2 gather from buckets: wave per dst node, ILP-4 ----------------
__global__ __launch_bounds__(256) void gather_k2(
    const unsigned short* __restrict__ Kb, const int* __restrict__ cnt,
    const int* __restrict__ esrc, unsigned short* __restrict__ K2b) {
  int w = threadIdx.x >> 6, lane = threadIdx.x & 63;
  int d = blockIdx.x * 4 + w;
  int n = cnt[d]; n = n > BCAP ? BCAP : n;
  const int* eb = esrc + d * BCAP;
  float a0 = 0, a1 = 0, a2 = 0, a3 = 0;
  int j = 0;
  for (; j + 4 <= n; j += 4) {     // 4 independent load chains in flight
    int s0 = eb[j], s1 = eb[j + 1], s2 = eb[j + 2], s3 = eb[j + 3];
    ushort4 k0 = *(const ushort4*)&Kb[s0 * DIM + lane * 4];
    ushort4 k1 = *(const ushort4*)&Kb[s1 * DIM + lane * 4];
    ushort4 k2 = *(const ushort4*)&Kb[s2 * DIM + lane * 4];
    ushort4 k3 = *(const ushort4*)&Kb[s3 * DIM + lane * 4];
    a0 += bf2f(k0.x) + bf2f(k1.x) + bf2f(k2.x) + bf2f(k3.x);
    a1 += bf2f(k0.y) + bf2f(k1.y) + bf2f(k2.y) + bf2f(k3.y);
    a2 += bf2f(k0.z) + bf2f(k1.z) + bf2f(k2.z) + bf2f(k3.z);
    a3 += bf2f(k0.w) + bf2f(k1.w) + bf2f(k2.w) + bf2f(k3.w);
  }
  for (; j < n; ++j) {
    int s = eb[j];
    ushort4 kv = *(const ushort4*)&Kb[s * DIM + lane * 4];
    a0 += bf2f(kv.x); a1 += bf2f(kv.y); a2 += bf2f(kv.z); a3 += bf2f(kv.w);
  }
  ushort4 o;
  o.x = bfbits(a0); o.y = bfbits(a1); o.z = bfbits(a2); o.w = bfbits(a3);
  *(ushort4*)&K2b[d * DIM + lane * 4] = o;
}

// ---- per-tile compute (64-key tile, 2 subs): QK^T -> exp2 -> pack/permlane -> PV ----
// r18: NO setprio (m190: setprio hurts barrier-lockstep multi-wave kernels).
static __device__ __forceinline__ void compute_tile64(
    const short* __restrict__ lk, const short* __restrict__ lv, int kl, int hi,
    short8 qf0, short8 qf1, const f32x16& zc, f32x16& o, float& lsum) {
#pragma unroll
  for (int sub = 0; sub < 2; ++sub) {
    const int base = sub * 32;
    short8 a0 = *(const short8*)&lk[(base + kl) * 40 + hi * 8];
    short8 a1 = *(const short8*)&lk[(base + kl) * 40 + 16 + hi * 8];
    f32x16 c = __builtin_amdgcn_mfma_f32_32x32x16_bf16(a0, qf0, zc, 0, 0, 0);
    c = __builtin_amdgcn_mfma_f32_32x32x16_bf16(a1, qf1, c, 0, 0, 0);
    float p[16];
#pragma unroll
    for (int r = 0; r < 16; ++r) p[r] = EXP2(c[r]);
    {  // scalar tree-sum
      float t0 = (p[0] + p[1]) + (p[2] + p[3]);
      float t1 = (p[4] + p[5]) + (p[6] + p[7]);
      float t2 = (p[8] + p[9]) + (p[10] + p[11]);
      float t3 = (p[12] + p[13]) + (p[14] + p[15]);
      lsum += (t0 + t1) + (t2 + t3);
    }
    unsigned X0 = pk_bf16(p[0], p[1]);
    unsigned Y0 = pk_bf16(p[2], p[3]);
    unsigned Z0 = pk_bf16(p[4], p[5]);
    unsigned W0 = pk_bf16(p[6], p[7]);
    asm volatile("v_permlane32_swap_b32 %0, %1" : "+v"(X0), "+v"(Z0));
    asm volatile("v_permlane32_swap_b32 %0, %1" : "+v"(Y0), "+v"(W0));
    unsigned X1 = pk_bf16(p[8], p[9]);
    unsigned Y1 = pk_bf16(p[10], p[11]);
    unsigned Z1 = pk_bf16(p[12], p[13]);
    unsigned W1 = pk_bf16(p[14], p[15]);
    asm volatile("v_permlane32_swap_b32 %0, %1" : "+v"(X1), "+v"(Z1));
    asm volatile("v_permlane32_swap_b32 %0, %1" : "+v"(Y1), "+v"(W1));
    short8 pb0, pb1;
    ((unsigned*)&pb0)[0] = X0; ((unsigned*)&pb0)[1] = Y0;
    ((unsigned*)&pb0)[2] = Z0; ((unsigned*)&pb0)[3] = W0;
    ((unsigned*)&pb1)[0] = X1; ((unsigned*)&pb1)[1] = Y1;
    ((unsigned*)&pb1)[2] = Z1; ((unsigned*)&pb1)[3] = W1;
    short8 va0 = *(const short8*)&lv[kl * 72 + base + hi * 8];
    short8 va1 = *(const short8*)&lv[kl * 72 + base + 16 + hi * 8];
    o = __builtin_amdgcn_mfma_f32_32x32x16_bf16(va0, pb0, o, 0, 0, 0);
    o = __builtin_amdgcn_mfma_f32_32x32x16_bf16(va1, pb1, o, 0, 0, 0);
  }
}

// ---------------- fused MFMA flash attention + merge ----------------
// r18: r14 geometry (grid (64,8), 512 thr = 2 q-waves x 4 zg, KVBLK=64 x 16 tiles)
// + LDS DOUBLE-BUFFER: ONE barrier per tile (16 total, was 32). Safety: between
// barrier(t) and barrier(t+1) a wave does {LOADKV(t+1), compute(t) on buf[t&1],
// STOREKV(t+1) into buf[(t+1)&1]} -- parities differ; compute(t-2) on the reused
// parity is sealed behind barrier(t-1). NO setprio (m190: hurts lockstep).
// LDS 78.8 KB -> 2 blocks/CU (= r14 residency). launch_bounds(512,4): cap 128.
__global__ __launch_bounds__(512, 4) void attn_fused(
    const unsigned short* __restrict__ Qb, const unsigned short* __restrict__ K2b,
    const unsigned short* __restrict__ Vtb, const float* __restrict__ inp,
    unsigned short* __restrict__ Hbf) {
  __shared__ __align__(16) char smem[77824];   // 4 zg x 2 buf x (lk[64][40]|lv[32][72])
  __shared__ float lbuf[4][64];
  const int tid = threadIdx.x;
  const int lane = tid & 63;
  const int wid = tid >> 6;
  const int qw = wid & 1;
  const int zg = wid >> 1;        // 0..3
  const int kl = lane & 31;
  const int hi = lane >> 5;
  const int gtid = tid & 127;
  const int h = blockIdx.y, hc = h * HDIM;
  const int q_local = qw * 32 + kl;
  const int q = blockIdx.x * 64 + q_local;
  const int ks0 = zg * 1024;

  short* base0 = (short*)(smem + zg * 19456);        // buf0: lk | lv
  short* base1 = (short*)(smem + zg * 19456 + 9728); // buf1

  const int kkey = gtid >> 1, kslot = gtid & 1;    // K: 2 thr/key
  const int vdim = gtid >> 3, vslot = gtid & 7;    // V: dims vdim, vdim+16
  const unsigned short* kg = &K2b[(ks0 + kkey) * DIM + hc + kslot * 16];
  const unsigned short* vg = &Vtb[(hc + vdim) * NN + ks0 + vslot * 8];
  const int lkoff = kkey * 40 + kslot * 16;        // within lk (2560 shorts)
  const int lvoff = 2560 + vdim * 72 + vslot * 8;  // within buffer, lv after lk

#define LOADKV(KR, VR)                                                      \
  do {                                                                      \
    KR[0] = *(const short8*)(kg);                                           \
    KR[1] = *(const short8*)(kg + 8);                                       \
    VR[0] = *(const short8*)(vg);                                           \
    VR[1] = *(const short8*)(vg + 16 * NN);                                 \
    kg += 64 * DIM; vg += 64;                                               \
  } while (0)
#define STOREKV(KR, VR, B)                                                  \
  do {                                                                      \
    *(short8*)((B) + lkoff) = KR[0];                                        \
    *(short8*)((B) + lkoff + 8) = KR[1];                                    \
    *(short8*)((B) + lvoff) = VR[0];                                        \
    *(short8*)((B) + lvoff + 16 * 72) = VR[1];                              \
  } while (0)

  short8 qf0 = *(const short8*)&Qb[q * DIM + hc + hi * 8];
  short8 qf1 = *(const short8*)&Qb[q * DIM + hc + 16 + hi * 8];

  f32x16 zc;
#pragma unroll
  for (int r = 0; r < 16; ++r) zc[r] = 0.f;
  f32x16 o = zc;
  float lsum = 0.f;

  short8 kr[2], vr[2];
  LOADKV(kr, vr);
#pragma unroll 1
  for (int t = 0; t < 16; ++t) {
    short* buf = (t & 1) ? base1 : base0;
    STOREKV(kr, vr, buf);            // write tile t (waits on its loads)
    __syncthreads();                 // tile t visible; prior-parity readers sealed
    if (t < 15) LOADKV(kr, vr);      // issue next tile's loads; land during compute
    compute_tile64(buf, buf + 2560, kl, hi, qf0, qf1, zc, o, lsum);
  }
#undef LOADKV
#undef STOREKV

  // in-block merge: o-frags + lsum partials through LDS (aliased over dead K/V bufs)
  float lt = lsum + __shfl_xor(lsum, 32);
  __syncthreads();                   // all waves done computing tile 15
  float* mz = (float*)smem + zg * 2208;            // [32 dims][69 q] per group
#pragma unroll
  for (int r = 0; r < 16; ++r) {
    int d = (r & 3) + 8 * (r >> 2) + 4 * hi;
    mz[d * 69 + q_local] = o[r];
  }
  if (hi == 0) lbuf[zg][q_local] = lt;
  __syncthreads();
  {
    int ql = tid >> 3;               // 0..63
    int dg = (tid & 7) * 4;          // 0..28
    float s = (lbuf[0][ql] + lbuf[1][ql]) + (lbuf[2][ql] + lbuf[3][ql]);
    float inv = 1.f / s;
    const float* mb = (const float*)smem;
    float acc[4];
#pragma unroll
    for (int i = 0; i < 4; ++i) {
      int off = (dg + i) * 69 + ql;
      acc[i] = (mb[off] + mb[2208 + off]) + (mb[4416 + off] + mb[6624 + off]);
    }
    int qg = blockIdx.x * 64 + ql;
    float4 in4 = *(const float4*)&inp[qg * DIM + hc + dg];
    ushort4 hb;
    hb.x = bfbits(in4.x + acc[0] * inv);
    hb.y = bfbits(in4.y + acc[1] * inv);
    hb.z = bfbits(in4.z + acc[2] * inv);
    hb.w = bfbits(in4.w + acc[3] * inv);
    *(ushort4*)&Hbf[qg * DIM + hc + dg] = hb;
  }
}

// ---------------- final GEMM (bf16 MFMA): out = H + leaky(H @ Wc + bc) ----------------
// Residual H read back from the staged sA tile (bf16) -- no Hf buffer.
__global__ __launch_bounds__(256) void gemm_final_mfma(
    const unsigned short* __restrict__ Hbf, const unsigned short* __restrict__ Wct,
    const float* __restrict__ bc, float* __restrict__ out) {
  __shared__ __align__(16) short sA[64 * 256];
  __shared__ __align__(16) short sB[64 * 256];
  const int tid = threadIdx.x;
  const int m0 = blockIdx.x * 64;
  const int n0 = blockIdx.y * 64;
#pragma unroll
  for (int i = 0; i < 8; ++i) {
    int idx = i * 256 + tid;
    int row = idx >> 5, slot = idx & 31;
    short8 v = *(const short8*)&Hbf[(m0 + row) * DIM + slot * 8];
    int byte = (slot * 16) ^ ((row & 15) << 4);
    *(short8*)((char*)sA + row * 512 + byte) = v;
  }
#pragma unroll
  for (int i = 0; i < 8; ++i) {
    int idx = i * 256 + tid;
    int row = idx >> 5, slot = idx & 31;
    short8 v = *(const short8*)&Wct[(n0 + row) * DIM + slot * 8];
    int byte = (slot * 16) ^ ((row & 15) << 4);
    *(short8*)((char*)sB + row * 512 + byte) = v;
  }
  __syncthreads();
  const int kl = tid & 31, hi = (tid & 63) >> 5, w = tid >> 6;
  const int rw = (w >> 1) * 32, cw = (w & 1) * 32;
  const int arow = rw + kl, brow = cw + kl;
  const int axor = (arow & 15) << 4, bxor = (brow & 15) << 4;
  const char* apA = (const char*)sA + arow * 512;
  const char* apB = (const char*)sB + brow * 512;
  f32x16 acc;
#pragma unroll
  for (int r = 0; r < 16; ++r) acc[r] = 0.f;
#pragma unroll
  for (int ks = 0; ks < 16; ++ks) {
    int cb = ks * 32 + hi * 16;
    short8 a = *(const short8*)(apA + (cb ^ axor));
    short8 b = *(const short8*)(apB + (cb ^ bxor));
    acc = __builtin_amdgcn_mfma_f32_32x32x16_bf16(a, b, acc, 0, 0, 0);
  }
#pragma unroll
  for (int r = 0; r < 16; ++r) {
    int mrow = (r & 3) + 8 * (r >> 2) + 4 * hi;
    int lrow = rw + mrow;
    int node = m0 + lrow, col = n0 + cw + kl;
    float x = acc[r] + bc[col];
    x = x > 0.f ? x : LEAKY * x;
    // residual from staged sA (Hbf tile, swizzle-consistent ushort read)
    unsigned short hr = *(const unsigned short*)(
        (const char*)sA + lrow * 512 + ((col * 2) ^ ((lrow & 15) << 4)));
    out[node * DIM + col] = bf2f(hr) + x;
  }
}

extern "C" void kernel_launch(void* const* d_in, const int* in_sizes, int n_in,
                              void* d_out, int out_size, void* d_ws, size_t ws_size,
                              hipStream_t stream) {
  const float* inp = (const float*)d_in[0];
  const int* src   = (const int*)d_in[1];
  const int* dst   = (const int*)d_in[2];
  const float* WQ  = (const float*)d_in[3];
  const float* WK  = (const float*)d_in[4];
  const float* WV  = (const float*)d_in[5];
  const float* Wc  = (const float*)d_in[6];
  const float* bc  = (const float*)d_in[7];
  float* out = (float*)d_out;
  const int E = in_sizes[1];

  // ws layout (~12.6 MB):
  char* ws = (char*)d_ws;
  unsigned short* Qb  = (unsigned short*)(ws);                      // 2 MB
  unsigned short* Kb  = (unsigned short*)(ws + 2  * 1024 * 1024);   // 2 MB
  unsigned short* Vtb = (unsigned short*)(ws + 4  * 1024 * 1024);   // 2 MB
  unsigned short* K2b = (unsigned short*)(ws + 6  * 1024 * 1024);   // 2 MB
  unsigned short* Wtb = (unsigned short*)(ws + 8  * 1024 * 1024);   // 512 KB
  unsigned short* Hbf = (unsigned short*)(ws + 8 * 1024 * 1024 + 524288);   // 2 MB
  int* cnt            = (int*)(ws + 10 * 1024 * 1024 + 524288);     // 16 KB
  int* esrc           = (int*)(ws + 10 * 1024 * 1024 + 540672);     // 2 MB (4096 x 128)

  const int fillBlocks = (E + 255) / 256;
  convert_w<<<dim3(16, 4), 256, 0, stream>>>(WQ, WK, WV, Wc, Wtb, cnt);
  gemm_fill<<<256 + fillBlocks, 256, 0, stream>>>(inp, Wtb, src, dst, E, cnt, esrc,
                                                  Qb, Kb, Vtb);
  gather_k2<<<NN / 4, 256, 0, stream>>>(Kb, cnt, esrc, K2b);
  attn_fused<<<dim3(64, 8), 512, 0, stream>>>(Qb, K2b, Vtb, inp, Hbf);
  gemm_final_mfma<<<dim3(64, 4), 256, 0, stream>>>(Hbf, Wtb + 3 * 65536, bc, out);
}

// Round 20
// 75.683 us; speedup vs baseline: 1.3358x; 1.0024x over previous
//
#include <hip/hip_runtime.h>
#include <hip/hip_bf16.h>
#include <math.h>

#define DIM 256
#define HDIM 32
#define NN 4096
#define NM (NN * DIM)
// (1/sqrt(256)) * log2(e) -- folded into WQ so scores are in exp2 domain
#define PREF 0.09016844005555896f
#define LEAKY 0.2f
#define BCAP 128   // edge-bucket capacity per dst (Poisson(32): P(deg>128) ~ 0)

typedef __attribute__((ext_vector_type(8))) short short8;
typedef __attribute__((ext_vector_type(16))) float f32x16;

#if __has_builtin(__builtin_amdgcn_exp2f)
#define EXP2(x) __builtin_amdgcn_exp2f(x)   // raw v_exp_f32: scores bounded, no fixups needed
#else
#define EXP2(x) exp2f(x)
#endif

static __device__ __forceinline__ unsigned bfbits(float x) {
  unsigned u = __float_as_uint(x);
  return (u + 0x7fffu + ((u >> 16) & 1u)) >> 16;   // RNE f32->bf16 bits
}
static __device__ __forceinline__ float bf2f(unsigned short b) {
  return __uint_as_float(((unsigned)b) << 16);
}
static __device__ __forceinline__ unsigned pk_bf16(float lo, float hi) {
  __hip_bfloat162 t = __float22bfloat162_rn(make_float2(lo, hi));  // v_cvt_pk_bf16_f32
  return *(unsigned*)&t;
}

// ---- convert: Wtb[w][n][k] = bf16(W_w[k][n]*scale); grid (16,4); y==0 blocks zero cnt
__global__ __launch_bounds__(256) void convert_w(
    const float* __restrict__ W0, const float* __restrict__ W1,
    const float* __restrict__ W2, const float* __restrict__ W3,
    unsigned short* __restrict__ Wtb, int* __restrict__ cnt) {
  const int tid = threadIdx.x;
  if (blockIdx.y == 0) cnt[blockIdx.x * 256 + tid] = 0;   // 16x256 = 4096 ints
  __shared__ float tile[64][68];
  const int wsel = blockIdx.y;
  const float* W = wsel == 0 ? W0 : (wsel == 1 ? W1 : (wsel == 2 ? W2 : W3));
  const float scale = wsel == 0 ? PREF : 1.f;
  const int kb = (blockIdx.x & 3) * 64, nb = (blockIdx.x >> 2) * 64;
#pragma unroll
  for (int i = 0; i < 4; ++i) {
    int idx = i * 256 + tid;
    int kr = idx >> 4, ns = idx & 15;
    float4 v = *(const float4*)&W[(kb + kr) * DIM + nb + ns * 4];
    tile[kr][ns * 4 + 0] = v.x; tile[kr][ns * 4 + 1] = v.y;
    tile[kr][ns * 4 + 2] = v.z; tile[kr][ns * 4 + 3] = v.w;
  }
  __syncthreads();
  unsigned short* o = Wtb + wsel * 65536;
#pragma unroll
  for (int i = 0; i < 2; ++i) {
    int idx = i * 256 + tid;
    int nr = idx >> 3, kslot = idx & 7;
    short8 v;
#pragma unroll
    for (int j = 0; j < 8; ++j)
      ((unsigned short*)&v)[j] = (unsigned short)bfbits(tile[kslot * 8 + j][nr] * scale);
    *(short8*)&o[(nb + nr) * DIM + kb + kslot * 8] = v;
  }
}

// ---------------- fused: QKV GEMM (blocks 0..255) + edge-bucket fill (blocks 256+) ----
__global__ __launch_bounds__(256) void gemm_fill(
    const float* __restrict__ inp, const unsigned short* __restrict__ Wtb,
    const int* __restrict__ src, const int* __restrict__ dst, int E,
    int* __restrict__ cnt, int* __restrict__ esrc,
    unsigned short* __restrict__ Qb, unsigned short* __restrict__ Kb,
    unsigned short* __restrict__ Vtb) {
  __shared__ __align__(16) short sA[64 * 256];   // 32 KB
  __shared__ __align__(16) short sB[64 * 256];   // 32 KB
  const int tid = threadIdx.x;
  const int b = blockIdx.x;
  if (b >= 256) {                  // fill: slot = atomicAdd(cnt[d]); esrc[d*BCAP+slot]=src
    int e = (b - 256) * 256 + tid;
    if (e < E) {
      int d = dst[e];
      int p = atomicAdd(&cnt[d], 1);
      if (p < BCAP) esrc[d * BCAP + p] = src[e];
    }
    return;
  }
  const int m0 = (b & 63) * 64;
  const int n0 = (b >> 6) * 64;
  // stage A once: f32 -> bf16 during copy (64 rows x 64 slots x 4 f32)
#pragma unroll
  for (int i = 0; i < 16; ++i) {
    int idx = i * 256 + tid;
    int row = idx >> 6, slot = idx & 63;
    float4 v = *(const float4*)&inp[(m0 + row) * DIM + slot * 4];
    uint2 pk = make_uint2(pk_bf16(v.x, v.y), pk_bf16(v.z, v.w));
    int byte = (slot * 8) ^ ((row & 15) << 4);
    *(uint2*)((char*)sA + row * 512 + byte) = pk;
  }
  const int kl = tid & 31, hi = (tid & 63) >> 5, w = tid >> 6;
  const int rw = (w >> 1) * 32, cw = (w & 1) * 32;
  const int arow = rw + kl, brow = cw + kl;
  const int axor = (arow & 15) << 4, bxor = (brow & 15) << 4;
  const char* apA = (const char*)sA + arow * 512;
  const char* apB = (const char*)sB + brow * 512;

#pragma unroll 1
  for (int wsel = 0; wsel < 3; ++wsel) {
    const unsigned short* Wt = Wtb + wsel * 65536;
    __syncthreads();               // prev compute done reading sB (wsel0: none)
#pragma unroll
    for (int i = 0; i < 8; ++i) {
      int idx = i * 256 + tid;
      int row = idx >> 5, slot = idx & 31;
      short8 v = *(const short8*)&Wt[(n0 + row) * DIM + slot * 8];
      int byte = (slot * 16) ^ ((row & 15) << 4);
      *(short8*)((char*)sB + row * 512 + byte) = v;
    }
    __syncthreads();               // sB (and sA on first iter) visible
    f32x16 acc;
#pragma unroll
    for (int r = 0; r < 16; ++r) acc[r] = 0.f;
#pragma unroll
    for (int ks = 0; ks < 16; ++ks) {
      int cb = ks * 32 + hi * 16;
      short8 a = *(const short8*)(apA + (cb ^ axor));
      short8 bfr = *(const short8*)(apB + (cb ^ bxor));
      acc = __builtin_amdgcn_mfma_f32_32x32x16_bf16(a, bfr, acc, 0, 0, 0);
    }
    if (wsel < 2) {
      unsigned short* C = wsel == 0 ? Qb : Kb;
#pragma unroll
      for (int r = 0; r < 16; ++r) {
        int mrow = (r & 3) + 8 * (r >> 2) + 4 * hi;
        C[(m0 + rw + mrow) * DIM + n0 + cw + kl] = (unsigned short)bfbits(acc[r]);
      }
    } else {
      // V: transpose via LDS (sB reused as [64 m][72] ushort tile) -> Vtb[dim][node]
      __syncthreads();             // all waves done reading sB
      unsigned short* tile = (unsigned short*)sB;
#pragma unroll
      for (int r = 0; r < 16; ++r) {
        int mrow = (r & 3) + 8 * (r >> 2) + 4 * hi;
        tile[(rw + mrow) * 72 + cw + kl] = (unsigned short)bfbits(acc[r]);
      }
      __syncthreads();
#pragma unroll
      for (int i = 0; i < 2; ++i) {
        int idx = i * 256 + tid;
        int drow = idx >> 3, nslot = idx & 7;
        short8 v;
#pragma unroll
        for (int j = 0; j < 8; ++j)
          ((unsigned short*)&v)[j] = tile[(nslot * 8 + j) * 72 + drow];
        *(short8*)&Vtb[(n0 + drow) * NN + m0 + nslot * 8] = v;
      }
    }
  }
}

// ---------------- K2 gather from buckets: wave per dst node, ILP-4 ----------------
__global__ __launch_bounds__(256) void gather_k2(
    const unsigned short* __restrict__ Kb, const int* __restrict__ cnt,
    const int* __restrict__ esrc, unsigned short* __restrict__ K2b) {
  int w = threadIdx.x >> 6, lane = threadIdx.x & 63;
  int d = blockIdx.x * 4 + w;
  int n = cnt[d]; n = n > BCAP ? BCAP : n;
  const int* eb = esrc + d * BCAP;
  float a0 = 0, a1 = 0, a2 = 0, a3 = 0;
  int j = 0;
  for (; j + 4 <= n; j += 4) {     // 4 independent load chains in flight
    int s0 = eb[j], s1 = eb[j + 1], s2 = eb[j + 2], s3 = eb[j + 3];
    ushort4 k0 = *(const ushort4*)&Kb[s0 * DIM + lane * 4];
    ushort4 k1 = *(const ushort4*)&Kb[s1 * DIM + lane * 4];
    ushort4 k2 = *(const ushort4*)&Kb[s2 * DIM + lane * 4];
    ushort4 k3 = *(const ushort4*)&Kb[s3 * DIM + lane * 4];
    a0 += bf2f(k0.x) + bf2f(k1.x) + bf2f(k2.x) + bf2f(k3.x);
    a1 += bf2f(k0.y) + bf2f(k1.y) + bf2f(k2.y) + bf2f(k3.y);
    a2 += bf2f(k0.z) + bf2f(k1.z) + bf2f(k2.z) + bf2f(k3.z);
    a3 += bf2f(k0.w) + bf2f(k1.w) + bf2f(k2.w) + bf2f(k3.w);
  }
  for (; j < n; ++j) {
    int s = eb[j];
    ushort4 kv = *(const ushort4*)&Kb[s * DIM + lane * 4];
    a0 += bf2f(kv.x); a1 += bf2f(kv.y); a2 += bf2f(kv.z); a3 += bf2f(kv.w);
  }
  ushort4 o;
  o.x = bfbits(a0); o.y = bfbits(a1); o.z = bfbits(a2); o.w = bfbits(a3);
  *(ushort4*)&K2b[d * DIM + lane * 4] = o;
}

// ---- per-tile compute, SUB-INTERLEAVED (r20): all 4 QK MFMAs -> both softmaxes
// (32 independent exp2s saturate the 1/4-rate trans pipe) -> all 4 PV MFMAs.
// Cuts one softmax-latency from the per-tile critical path vs the serial 2-sub form.
static __device__ __forceinline__ void compute_tile64(
    const short* __restrict__ lk, const short* __restrict__ lv, int kl, int hi,
    short8 qf0, short8 qf1, f32x16& o, float& lsum) {
  short8 a00 = *(const short8*)&lk[(kl) * 40 + hi * 8];
  short8 a01 = *(const short8*)&lk[(kl) * 40 + 16 + hi * 8];
  short8 a10 = *(const short8*)&lk[(32 + kl) * 40 + hi * 8];
  short8 a11 = *(const short8*)&lk[(32 + kl) * 40 + 16 + hi * 8];
  f32x16 c0, c1;
#pragma unroll
  for (int r = 0; r < 16; ++r) { c0[r] = 0.f; c1[r] = 0.f; }
  c0 = __builtin_amdgcn_mfma_f32_32x32x16_bf16(a00, qf0, c0, 0, 0, 0);
  c0 = __builtin_amdgcn_mfma_f32_32x32x16_bf16(a01, qf1, c0, 0, 0, 0);
  c1 = __builtin_amdgcn_mfma_f32_32x32x16_bf16(a10, qf0, c1, 0, 0, 0);
  c1 = __builtin_amdgcn_mfma_f32_32x32x16_bf16(a11, qf1, c1, 0, 0, 0);
  float p0[16], p1[16];
#pragma unroll
  for (int r = 0; r < 16; ++r) p0[r] = EXP2(c0[r]);
#pragma unroll
  for (int r = 0; r < 16; ++r) p1[r] = EXP2(c1[r]);
  {  // scalar tree-sums (independent -> ILP)
    float t0 = (p0[0] + p0[1]) + (p0[2] + p0[3]);
    float t1 = (p0[4] + p0[5]) + (p0[6] + p0[7]);
    float t2 = (p0[8] + p0[9]) + (p0[10] + p0[11]);
    float t3 = (p0[12] + p0[13]) + (p0[14] + p0[15]);
    float u0 = (p1[0] + p1[1]) + (p1[2] + p1[3]);
    float u1 = (p1[4] + p1[5]) + (p1[6] + p1[7]);
    float u2 = (p1[8] + p1[9]) + (p1[10] + p1[11]);
    float u3 = (p1[12] + p1[13]) + (p1[14] + p1[15]);
    lsum += ((t0 + t1) + (t2 + t3)) + ((u0 + u1) + (u2 + u3));
  }
  unsigned X0 = pk_bf16(p0[0], p0[1]);
  unsigned Y0 = pk_bf16(p0[2], p0[3]);
  unsigned Z0 = pk_bf16(p0[4], p0[5]);
  unsigned W0 = pk_bf16(p0[6], p0[7]);
  asm volatile("v_permlane32_swap_b32 %0, %1" : "+v"(X0), "+v"(Z0));
  asm volatile("v_permlane32_swap_b32 %0, %1" : "+v"(Y0), "+v"(W0));
  unsigned X1 = pk_bf16(p0[8], p0[9]);
  unsigned Y1 = pk_bf16(p0[10], p0[11]);
  unsigned Z1 = pk_bf16(p0[12], p0[13]);
  unsigned W1 = pk_bf16(p0[14], p0[15]);
  asm volatile("v_permlane32_swap_b32 %0, %1" : "+v"(X1), "+v"(Z1));
  asm volatile("v_permlane32_swap_b32 %0, %1" : "+v"(Y1), "+v"(W1));
  short8 pb00, pb01;
  ((unsigned*)&pb00)[0] = X0; ((unsigned*)&pb00)[1] = Y0;
  ((unsigned*)&pb00)[2] = Z0; ((unsigned*)&pb00)[3] = W0;
  ((unsigned*)&pb01)[0] = X1; ((unsigned*)&pb01)[1] = Y1;
  ((unsigned*)&pb01)[2] = Z1; ((unsigned*)&pb01)[3] = W1;
  unsigned X2 = pk_bf16(p1[0], p1[1]);
  unsigned Y2 = pk_bf16(p1[2], p1[3]);
  unsigned Z2 = pk_bf16(p1[4], p1[5]);
  unsigned W2 = pk_bf16(p1[6], p1[7]);
  asm volatile("v_permlane32_swap_b32 %0, %1" : "+v"(X2), "+v"(Z2));
  asm volatile("v_permlane32_swap_b32 %0, %1" : "+v"(Y2), "+v"(W2));
  unsigned X3 = pk_bf16(p1[8], p1[9]);
  unsigned Y3 = pk_bf16(p1[10], p1[11]);
  unsigned Z3 = pk_bf16(p1[12], p1[13]);
  unsigned W3 = pk_bf16(p1[14], p1[15]);
  asm volatile("v_permlane32_swap_b32 %0, %1" : "+v"(X3), "+v"(Z3));
  asm volatile("v_permlane32_swap_b32 %0, %1" : "+v"(Y3), "+v"(W3));
  short8 pb10, pb11;
  ((unsigned*)&pb10)[0] = X2; ((unsigned*)&pb10)[1] = Y2;
  ((unsigned*)&pb10)[2] = Z2; ((unsigned*)&pb10)[3] = W2;
  ((unsigned*)&pb11)[0] = X3; ((unsigned*)&pb11)[1] = Y3;
  ((unsigned*)&pb11)[2] = Z3; ((unsigned*)&pb11)[3] = W3;
  short8 va00 = *(const short8*)&lv[kl * 72 + hi * 8];
  short8 va01 = *(const short8*)&lv[kl * 72 + 16 + hi * 8];
  short8 va10 = *(const short8*)&lv[kl * 72 + 32 + hi * 8];
  short8 va11 = *(const short8*)&lv[kl * 72 + 48 + hi * 8];
  o = __builtin_amdgcn_mfma_f32_32x32x16_bf16(va00, pb00, o, 0, 0, 0);
  o = __builtin_amdgcn_mfma_f32_32x32x16_bf16(va01, pb01, o, 0, 0, 0);
  o = __builtin_amdgcn_mfma_f32_32x32x16_bf16(va10, pb10, o, 0, 0, 0);
  o = __builtin_amdgcn_mfma_f32_32x32x16_bf16(va11, pb11, o, 0, 0, 0);
}

// ---------------- fused MFMA flash attention + merge ----------------
// r20: r18 geometry/dbuf verbatim (grid (64,8), 512 thr = 2 q-waves x 4 zg,
// KVBLK=64 x 16 tiles, dbuf LDS 78.8KB -> 2 blocks/CU, 1 barrier/tile);
// compute_tile64 sub-interleaved; zc dropped (VGPR headroom for c0+c1 under 128 cap).
__global__ __launch_bounds__(512, 4) void attn_fused(
    const unsigned short* __restrict__ Qb, const unsigned short* __restrict__ K2b,
    const unsigned short* __restrict__ Vtb, const float* __restrict__ inp,
    unsigned short* __restrict__ Hbf) {
  __shared__ __align__(16) char smem[77824];   // 4 zg x 2 buf x (lk[64][40]|lv[32][72])
  __shared__ float lbuf[4][64];
  const int tid = threadIdx.x;
  const int lane = tid & 63;
  const int wid = tid >> 6;
  const int qw = wid & 1;
  const int zg = wid >> 1;        // 0..3
  const int kl = lane & 31;
  const int hi = lane >> 5;
  const int gtid = tid & 127;
  const int h = blockIdx.y, hc = h * HDIM;
  const int q_local = qw * 32 + kl;
  const int q = blockIdx.x * 64 + q_local;
  const int ks0 = zg * 1024;

  short* base0 = (short*)(smem + zg * 19456);        // buf0: lk | lv
  short* base1 = (short*)(smem + zg * 19456 + 9728); // buf1

  const int kkey = gtid >> 1, kslot = gtid & 1;    // K: 2 thr/key
  const int vdim = gtid >> 3, vslot = gtid & 7;    // V: dims vdim, vdim+16
  const unsigned short* kg = &K2b[(ks0 + kkey) * DIM + hc + kslot * 16];
  const unsigned short* vg = &Vtb[(hc + vdim) * NN + ks0 + vslot * 8];
  const int lkoff = kkey * 40 + kslot * 16;        // within lk (2560 shorts)
  const int lvoff = 2560 + vdim * 72 + vslot * 8;  // within buffer, lv after lk

#define LOADKV(KR, VR)                                                      \
  do {                                                                      \
    KR[0] = *(const short8*)(kg);                                           \
    KR[1] = *(const short8*)(kg + 8);                                       \
    VR[0] = *(const short8*)(vg);                                           \
    VR[1] = *(const short8*)(vg + 16 * NN);                                 \
    kg += 64 * DIM; vg += 64;                                               \
  } while (0)
#define STOREKV(KR, VR, B)                                                  \
  do {                                                                      \
    *(short8*)((B) + lkoff) = KR[0];                                        \
    *(short8*)((B) + lkoff + 8) = KR[1];                                    \
    *(short8*)((B) + lvoff) = VR[0];                                        \
    *(short8*)((B) + lvoff + 16 * 72) = VR[1];                              \
  } while (0)

  short8 qf0 = *(const short8*)&Qb[q * DIM + hc + hi * 8];
  short8 qf1 = *(const short8*)&Qb[q * DIM + hc + 16 + hi * 8];

  f32x16 o;
#pragma unroll
  for (int r = 0; r < 16; ++r) o[r] = 0.f;
  float lsum = 0.f;

  short8 kr[2], vr[2];
  LOADKV(kr, vr);
#pragma unroll 1
  for (int t = 0; t < 16; ++t) {
    short* buf = (t & 1) ? base1 : base0;
    STOREKV(kr, vr, buf);            // write tile t (waits on its loads)
    __syncthreads();                 // tile t visible; prior-parity readers sealed
    if (t < 15) LOADKV(kr, vr);      // issue next tile's loads; land during compute
    compute_tile64(buf, buf + 2560, kl, hi, qf0, qf1, o, lsum);
  }
#undef LOADKV
#undef STOREKV

  // in-block merge: o-frags + lsum partials through LDS (aliased over dead K/V bufs)
  float lt = lsum + __shfl_xor(lsum, 32);
  __syncthreads();                   // all waves done computing tile 15
  float* mz = (float*)smem + zg * 2208;            // [32 dims][69 q] per group
#pragma unroll
  for (int r = 0; r < 16; ++r) {
    int d = (r & 3) + 8 * (r >> 2) + 4 * hi;
    mz[d * 69 + q_local] = o[r];
  }
  if (hi == 0) lbuf[zg][q_local] = lt;
  __syncthreads();
  {
    int ql = tid >> 3;               // 0..63
    int dg = (tid & 7) * 4;          // 0..28
    float s = (lbuf[0][ql] + lbuf[1][ql]) + (lbuf[2][ql] + lbuf[3][ql]);
    float inv = 1.f / s;
    const float* mb = (const float*)smem;
    float acc[4];
#pragma unroll
    for (int i = 0; i < 4; ++i) {
      int off = (dg + i) * 69 + ql;
      acc[i] = (mb[off] + mb[2208 + off]) + (mb[4416 + off] + mb[6624 + off]);
    }
    int qg = blockIdx.x * 64 + ql;
    float4 in4 = *(const float4*)&inp[qg * DIM + hc + dg];
    ushort4 hb;
    hb.x = bfbits(in4.x + acc[0] * inv);
    hb.y = bfbits(in4.y + acc[1] * inv);
    hb.z = bfbits(in4.z + acc[2] * inv);
    hb.w = bfbits(in4.w + acc[3] * inv);
    *(ushort4*)&Hbf[qg * DIM + hc + dg] = hb;
  }
}

// ---------------- final GEMM (bf16 MFMA): out = H + leaky(H @ Wc + bc) ----------------
// Residual H read back from the staged sA tile (bf16) -- no Hf buffer.
__global__ __launch_bounds__(256) void gemm_final_mfma(
    const unsigned short* __restrict__ Hbf, const unsigned short* __restrict__ Wct,
    const float* __restrict__ bc, float* __restrict__ out) {
  __shared__ __align__(16) short sA[64 * 256];
  __shared__ __align__(16) short sB[64 * 256];
  const int tid = threadIdx.x;
  const int m0 = blockIdx.x * 64;
  const int n0 = blockIdx.y * 64;
#pragma unroll
  for (int i = 0; i < 8; ++i) {
    int idx = i * 256 + tid;
    int row = idx >> 5, slot = idx & 31;
    short8 v = *(const short8*)&Hbf[(m0 + row) * DIM + slot * 8];
    int byte = (slot * 16) ^ ((row & 15) << 4);
    *(short8*)((char*)sA + row * 512 + byte) = v;
  }
#pragma unroll
  for (int i = 0; i < 8; ++i) {
    int idx = i * 256 + tid;
    int row = idx >> 5, slot = idx & 31;
    short8 v = *(const short8*)&Wct[(n0 + row) * DIM + slot * 8];
    int byte = (slot * 16) ^ ((row & 15) << 4);
    *(short8*)((char*)sB + row * 512 + byte) = v;
  }
  __syncthreads();
  const int kl = tid & 31, hi = (tid & 63) >> 5, w = tid >> 6;
  const int rw = (w >> 1) * 32, cw = (w & 1) * 32;
  const int arow = rw + kl, brow = cw + kl;
  const int axor = (arow & 15) << 4, bxor = (brow & 15) << 4;
  const char* apA = (const char*)sA + arow * 512;
  const char* apB = (const char*)sB + brow * 512;
  f32x16 acc;
#pragma unroll
  for (int r = 0; r < 16; ++r) acc[r] = 0.f;
#pragma unroll
  for (int ks = 0; ks < 16; ++ks) {
    int cb = ks * 32 + hi * 16;
    short8 a = *(const short8*)(apA + (cb ^ axor));
    short8 b = *(const short8*)(apB + (cb ^ bxor));
    acc = __builtin_amdgcn_mfma_f32_32x32x16_bf16(a, b, acc, 0, 0, 0);
  }
#pragma unroll
  for (int r = 0; r < 16; ++r) {
    int mrow = (r & 3) + 8 * (r >> 2) + 4 * hi;
    int lrow = rw + mrow;
    int node = m0 + lrow, col = n0 + cw + kl;
    float x = acc[r] + bc[col];
    x = x > 0.f ? x : LEAKY * x;
    // residual from staged sA (Hbf tile, swizzle-consistent ushort read)
    unsigned short hr = *(const unsigned short*)(
        (const char*)sA + lrow * 512 + ((col * 2) ^ ((lrow & 15) << 4)));
    out[node * DIM + col] = bf2f(hr) + x;
  }
}

extern "C" void kernel_launch(void* const* d_in, const int* in_sizes, int n_in,
                              void* d_out, int out_size, void* d_ws, size_t ws_size,
                              hipStream_t stream) {
  const float* inp = (const float*)d_in[0];
  const int* src   = (const int*)d_in[1];
  const int* dst   = (const int*)d_in[2];
  const float* WQ  = (const float*)d_in[3];
  const float* WK  = (const float*)d_in[4];
  const float* WV  = (const float*)d_in[5];
  const float* Wc  = (const float*)d_in[6];
  const float* bc  = (const float*)d_in[7];
  float* out = (float*)d_out;
  const int E = in_sizes[1];

  // ws layout (~12.6 MB):
  char* ws = (char*)d_ws;
  unsigned short* Qb  = (unsigned short*)(ws);                      // 2 MB
  unsigned short* Kb  = (unsigned short*)(ws + 2  * 1024 * 1024);   // 2 MB
  unsigned short* Vtb = (unsigned short*)(ws + 4  * 1024 * 1024);   // 2 MB
  unsigned short* K2b = (unsigned short*)(ws + 6  * 1024 * 1024);   // 2 MB
  unsigned short* Wtb = (unsigned short*)(ws + 8  * 1024 * 1024);   // 512 KB
  unsigned short* Hbf = (unsigned short*)(ws + 8 * 1024 * 1024 + 524288);   // 2 MB
  int* cnt            = (int*)(ws + 10 * 1024 * 1024 + 524288);     // 16 KB
  int* esrc           = (int*)(ws + 10 * 1024 * 1024 + 540672);     // 2 MB (4096 x 128)

  const int fillBlocks = (E + 255) / 256;
  convert_w<<<dim3(16, 4), 256, 0, stream>>>(WQ, WK, WV, Wc, Wtb, cnt);
  gemm_fill<<<256 + fillBlocks, 256, 0, stream>>>(inp, Wtb, src, dst, E, cnt, esrc,
                                                  Qb, Kb, Vtb);
  gather_k2<<<NN / 4, 256, 0, stream>>>(Kb, cnt, esrc, K2b);
  attn_fused<<<dim3(64, 8), 512, 0, stream>>>(Qb, K2b, Vtb, inp, Hbf);
  gemm_final_mfma<<<dim3(64, 4), 256, 0, stream>>>(Hbf, Wtb + 3 * 65536, bc, out);
}